// Round 3
// baseline (73.302 us; speedup 1.0000x reference)
//
#include <hip/hip_runtime.h>

// WaveletFeatures: pywt.wavedec(x, 'db4', level=3, mode='symmetric') per row.
// out = concat([cA3, cD3, cD2, cD1]), each [B, Mk] row-major, flat fp32.
// y[m] = sum_{s=0..7} f[s] * x_sym[2m+1-s];  sym: o<0 -> -1-o ; o>=n -> 2n-1-o.
//
// R3: NT=512 (same 24.6KB LDS now carries 8 waves -> 4 blocks/CU = 32 waves =
// 100% occupancy, forced <=64 VGPR); W8 level-1 chunks (6 dwordx4 per 8
// outputs); nontemporal output stores so the 135MB output doesn't evict the
// 134MB input from L3 (input stays L3-resident across graph replays).

constexpr int N0 = 8192;
constexpr int M1 = 4099;  // floor((8192+7)/2)
constexpr int M2 = 2053;
constexpr int M3 = 1030;
constexpr int NT = 512;

constexpr int C1 = 511;  // W8: i0 = 4+8c <= 4084, covers outputs 4..4091
constexpr int C2 = 511;  // W4: i0 = 4+4c <= 2044, covers 4..2047
constexpr int C3 = 255;  // W4: i0 = 4+4c <= 1020, covers 4..1023

__device__ __forceinline__ int symidx(int o, int n) {
    if (o < 0) o = -1 - o;
    if (o >= n) o = 2 * n - 1 - o;  // single reflection (overhang <= 6)
    return o;
}

// 4 output pairs from w[k] = in[2*i0 - 8 + k], k=0..15:
// y[i0+j] = sum_t RF[t] * w[2j+2+t], RF = reversed filter.
__device__ __forceinline__ void compute4(const float* __restrict__ w,
                                         float* __restrict__ a,
                                         float* __restrict__ d) {
    constexpr float RLO[8] = {0.23037781330885523f,  0.7148465705525415f,
                              0.6308807679295904f,   -0.02798376941698385f,
                              -0.18703481171888114f, 0.030841381835986965f,
                              0.032883011666982945f, -0.010597401784997278f};
    constexpr float RHI[8] = {-0.010597401784997278f, -0.032883011666982945f,
                              0.030841381835986965f,  0.18703481171888114f,
                              -0.02798376941698385f,  -0.6308807679295904f,
                              0.7148465705525415f,    -0.23037781330885523f};
#pragma unroll
    for (int j = 0; j < 4; ++j) {
        float aj = 0.f, dj = 0.f;
#pragma unroll
        for (int t = 0; t < 8; ++t) {
            const float v = w[2 * j + 2 + t];
            aj = fmaf(RLO[t], v, aj);
            dj = fmaf(RHI[t], v, dj);
        }
        a[j] = aj;
        d[j] = dj;
    }
}

__device__ __forceinline__ void edge_pair(const float* in, int n, int i,
                                          float& a, float& d) {
    constexpr float LO[8] = {
        -0.010597401784997278f, 0.032883011666982945f, 0.030841381835986965f,
        -0.18703481171888114f,  -0.02798376941698385f, 0.6308807679295904f,
        0.7148465705525415f,    0.23037781330885523f};
    constexpr float HI[8] = {
        -0.23037781330885523f,  0.7148465705525415f,   -0.6308807679295904f,
        -0.02798376941698385f,  0.18703481171888114f,  0.030841381835986965f,
        -0.032883011666982945f, -0.010597401784997278f};
    a = 0.f;
    d = 0.f;
#pragma unroll
    for (int s = 0; s < 8; ++s) {
        const float v = in[symidx(2 * i + 1 - s, n)];
        a = fmaf(LO[s], v, a);
        d = fmaf(HI[s], v, d);
    }
}

__global__ __launch_bounds__(NT, 8) void WaveletFeatures_77214922047612_kernel(
    const float* __restrict__ x, float* __restrict__ out, int B) {
    __shared__ __align__(16) float s1[M1 + 1];  // cA1
    __shared__ __align__(16) float s2[M2 + 3];  // cA2

    const int row = blockIdx.x;
    const int tid = threadIdx.x;
    const float* xr = x + (size_t)row * N0;

    float* ca3 = out + (size_t)row * M3;
    float* cd3 = out + (size_t)B * M3 + (size_t)row * M3;
    float* cd2 = out + 2 * (size_t)B * M3 + (size_t)row * M2;
    float* cd1 = out + (size_t)B * (2 * M3 + M2) + (size_t)row * M1;

    // ---------- level 1: x (global, n=8192) -> cA1 in s1, cD1 -> global ----
    if (tid < C1) {  // one W8 chunk per thread
        const int i0 = 4 + 8 * tid;
        float w[24];
        const float4* p = reinterpret_cast<const float4*>(xr + 2 * i0 - 8);
#pragma unroll
        for (int k = 0; k < 6; ++k)
            *reinterpret_cast<float4*>(&w[4 * k]) = p[k];
        float a[8], d[8];
        compute4(w, a, d);
        compute4(w + 8, a + 4, d + 4);
        *reinterpret_cast<float4*>(&s1[i0]) = make_float4(a[0], a[1], a[2], a[3]);
        *reinterpret_cast<float4*>(&s1[i0 + 4]) =
            make_float4(a[4], a[5], a[6], a[7]);
#pragma unroll
        for (int j = 0; j < 8; ++j)
            __builtin_nontemporal_store(d[j], &cd1[i0 + j]);
    }
    if (tid < 11) {  // edges: {0..3, 4092..4098}
        const int i = tid < 4 ? tid : 4088 + tid;
        float a, d;
        edge_pair(xr, N0, i, a, d);
        s1[i] = a;
        __builtin_nontemporal_store(d, &cd1[i]);
    }
    __syncthreads();

    // ---------- level 2: s1 (n=4099) -> cA2 in s2, cD2 -> global ----------
    if (tid < C2) {
        const int i0 = 4 + 4 * tid;
        float w[16];
        const float4* p = reinterpret_cast<const float4*>(&s1[2 * i0 - 8]);
#pragma unroll
        for (int k = 0; k < 4; ++k)
            *reinterpret_cast<float4*>(&w[4 * k]) = p[k];
        float a[4], d[4];
        compute4(w, a, d);
        *reinterpret_cast<float4*>(&s2[i0]) = make_float4(a[0], a[1], a[2], a[3]);
#pragma unroll
        for (int j = 0; j < 4; ++j)
            __builtin_nontemporal_store(d[j], &cd2[i0 + j]);
    }
    if (tid < 9) {  // edges: {0..3, 2048..2052}
        const int i = tid < 4 ? tid : 2044 + tid;
        float a, d;
        edge_pair(s1, M1, i, a, d);
        s2[i] = a;
        __builtin_nontemporal_store(d, &cd2[i]);
    }
    __syncthreads();

    // ---------- level 3: s2 (n=2053) -> cA3, cD3 -> global ----------------
    if (tid < C3) {
        const int i0 = 4 + 4 * tid;
        float w[16];
        const float4* p = reinterpret_cast<const float4*>(&s2[2 * i0 - 8]);
#pragma unroll
        for (int k = 0; k < 4; ++k)
            *reinterpret_cast<float4*>(&w[4 * k]) = p[k];
        float a[4], d[4];
        compute4(w, a, d);
#pragma unroll
        for (int j = 0; j < 4; ++j) {
            __builtin_nontemporal_store(a[j], &ca3[i0 + j]);
            __builtin_nontemporal_store(d[j], &cd3[i0 + j]);
        }
    }
    if (tid < 10) {  // edges: {0..3, 1024..1029}
        const int i = tid < 4 ? tid : 1020 + tid;
        float a, d;
        edge_pair(s2, M2, i, a, d);
        __builtin_nontemporal_store(a, &ca3[i]);
        __builtin_nontemporal_store(d, &cd3[i]);
    }
}

extern "C" void kernel_launch(void* const* d_in, const int* in_sizes, int n_in,
                              void* d_out, int out_size, void* d_ws,
                              size_t ws_size, hipStream_t stream) {
    const float* x = (const float*)d_in[0];
    float* out = (float*)d_out;
    const int B = in_sizes[0] / N0;  // 4096
    WaveletFeatures_77214922047612_kernel<<<dim3(B), dim3(NT), 0, stream>>>(
        x, out, B);
}